// Round 4
// baseline (1006.776 us; speedup 1.0000x reference)
//
#include <hip/hip_runtime.h>
#include <hip/hip_bf16.h>
#include <math.h>

#define DI __device__ __forceinline__

typedef float  f32x4 __attribute__((ext_vector_type(4)));
typedef short  bf8   __attribute__((ext_vector_type(8)));
typedef unsigned short u16;

static constexpr int TT = 8192;   // T edges
static constexpr int KK = 32;     // CN tokens per edge
static constexpr int CC = 128;    // channels

DI u16 f2bf(float x){ union{float f; unsigned u;} v; v.f = x; unsigned r = v.u + 0x7FFFu + ((v.u>>16)&1u); return (u16)(r>>16); }
DI float bf2f(u16 b){ union{unsigned u; float f;} v; v.u = ((unsigned)b)<<16; return v.f; }
DI unsigned pk2(float a, float b){ return (unsigned)f2bf(a) | ((unsigned)f2bf(b)<<16); }
DI f32x4 mfma16(bf8 a, bf8 b, f32x4 c){ return __builtin_amdgcn_mfma_f32_16x16x32_bf16(a, b, c, 0, 0, 0); }
// swizzled LDS byte offset: row-major [*][stride bytes], xor row bits into 16B-slot bits
DI int soff(int r, int c, int stride, int mask){ return r*stride + ((c*2) ^ ((r&mask)<<4)); }

// ------------------------------------------------------------------
// K0: convert weights fp32 -> bf16 blob in MFMA fragment order (unchanged).
// ------------------------------------------------------------------
struct WP { const float* p[12]; };

__global__ void k0_convert(WP wp, u16* __restrict__ dst){
  const int KS[11]  = {512,128,128,128,512,128,256,256,128,256,256};
  const int SH[11]  = {4,2,2,2,4,2,3,3,2,3,3};   // log2(K/32)
  const int OFF[12] = {0,65536,114688,131072,196608,262144,294912,360448,425984,458752,524288,589824};
  int gid = blockIdx.x*256 + threadIdx.x;        // 2305*256 = 590080
  if (gid >= 590080) return;
  if (gid >= 589824){ dst[gid] = f2bf(wp.p[11][gid - 589824]); return; }   // lin_w2 linear
  #pragma unroll
  for (int s = 0; s < 11; s++){
    if (gid < OFF[s+1]){
      int i = gid - OFF[s];
      int e = i & 7, l = (i >> 3) & 63, t = i >> 9;
      int k32 = t & ((1 << SH[s]) - 1), n16 = t >> SH[s];
      int row = n16*16 + (l & 15);
      int col = k32*32 + ((l >> 4) << 3) + e;
      dst[gid] = f2bf(wp.p[s][row*KS[s] + col]);
      return;
    }
  }
}

// ------------------------------------------------------------------
// K1: fused, m-split: wave w owns token rows [16w,16w+16) for all GEMMs;
// attention: wave w = (edge w>>1, heads (w&1)*4..+4), fully wave-private.
// 5 __syncthreads per block (was 23).
// ------------------------------------------------------------------
#define O_TOK 0        // [64][128] bf16 sw(256,7)  16K  residual (+pool partials at end)
#define O_H   16384    // [64][128] bf16 sw(256,7)  16K  ln out / xw staging
#define O_RG  32768    // 20480B multi-use:
                       //  phase0: xibuf u32[2][3][64] @+512
                       //  attn:   per-wave 5120B: Q[32][32B] K[32][32B] VT[16][64B] ATT[32][64B]
                       //  ctx:    CTX [64][128] sw(256,7) @+0 (16K)
                       //  ff:     per-wave gelu buf [16][256B] @ w*4096
#define LDS_K1 53248

DI void layernorm64(const char* src, char* dst, const float* __restrict__ g,
                    const float* __restrict__ bta, int tid){
  int r = tid >> 2, q = tid & 3;
  float v[32]; float s = 0.f, sq = 0.f;
  #pragma unroll
  for (int i = 0; i < 4; i++){
    bf8 h8 = *(const bf8*)(src + soff(r, q*32 + i*8, 256, 7));
    #pragma unroll
    for (int j = 0; j < 8; j++){ float f = bf2f((u16)h8[j]); v[i*8+j] = f; s += f; sq += f*f; }
  }
  s  += __shfl_xor(s, 1);  s  += __shfl_xor(s, 2);
  sq += __shfl_xor(sq, 1); sq += __shfl_xor(sq, 2);
  float mu = s * (1.f/128.f);
  float rstd = rsqrtf(sq*(1.f/128.f) - mu*mu + 1e-5f);
  #pragma unroll
  for (int i = 0; i < 4; i++){
    bf8 o;
    #pragma unroll
    for (int j = 0; j < 8; j++){
      int c = q*32 + i*8 + j;
      o[j] = (short)f2bf((v[i*8+j] - mu)*rstd*g[c] + bta[c]);
    }
    *(bf8*)(dst + soff(r, q*32 + i*8, 256, 7)) = o;
  }
}

__global__ __launch_bounds__(256, 3)
void k1_fused(const float* __restrict__ x, const int* __restrict__ tar_ei,
              const int* __restrict__ cn_cols, const int* __restrict__ cn_counts,
              const float* __restrict__ tok_b,
              const float* __restrict__ ln1_g, const float* __restrict__ ln1_b,
              const float* __restrict__ qkv_b, const float* __restrict__ out_b,
              const float* __restrict__ ln2_g, const float* __restrict__ ln2_b,
              const float* __restrict__ ff1_b, const float* __restrict__ ff2_b,
              const u16* __restrict__ wbf,
              float* __restrict__ xcn_out, float* __restrict__ xij_out)
{
  __shared__ __align__(16) char sm[LDS_K1];
  const int tid = threadIdx.x;
  const int w = tid >> 6, l = tid & 63, l15 = l & 15, lg = l >> 4;
  const int t0 = blockIdx.x * 2;
  const int e_w = w >> 1, hh_w = w & 1;

  const u16* wtok = wbf;            // [128][512] frag-order
  const u16* wqkv = wbf + 65536;    // [384][128]
  const u16* wout = wbf + 114688;   // [128][128]
  const u16* wff1 = wbf + 131072;   // [512][128]
  const u16* wff2 = wbf + 196608;   // [128][512]

  const f32x4 zf = {0.f, 0.f, 0.f, 0.f};
  const int cnt_e = cn_counts[t0 + e_w];

  // ---- phase 0a: gather xw -> sH (rows private to wave: r = tid>>2)
  {
    int r = tid >> 2, q = tid & 3;
    int col = cn_cols[(t0 + (r >> 5))*KK + (r & 31)];
    const float4* xs = (const float4*)(x + (size_t)col*CC) + q*8;
    #pragma unroll
    for (int i = 0; i < 4; i++){
      float4 a = xs[2*i], b = xs[2*i+1];
      bf8 v;
      v[0]=(short)f2bf(a.x); v[1]=(short)f2bf(a.y); v[2]=(short)f2bf(a.z); v[3]=(short)f2bf(a.w);
      v[4]=(short)f2bf(b.x); v[5]=(short)f2bf(b.y); v[6]=(short)f2bf(b.z); v[7]=(short)f2bf(b.w);
      *(bf8*)(sm + O_H + soff(r, q*32 + i*8, 256, 7)) = v;
    }
  }
  // ---- phase 0b: stage xi/xj/xi*xj broadcast rows + write xij (waves 0-1)
  if (w < 2){
    int e = w, c0 = l*2;
    int ti = tar_ei[t0 + e], tj = tar_ei[TT + t0 + e];
    float vix = x[(size_t)ti*CC + c0], viy = x[(size_t)ti*CC + c0 + 1];
    float vjx = x[(size_t)tj*CC + c0], vjy = x[(size_t)tj*CC + c0 + 1];
    float px = vix*vjx, py = viy*vjy;
    xij_out[(size_t)(t0+e)*CC + c0]     = px;
    xij_out[(size_t)(t0+e)*CC + c0 + 1] = py;
    unsigned* xb = (unsigned*)(sm + O_RG + 512) + e*192;   // [3][64] u32
    xb[l]       = pk2(vix, viy);
    xb[64 + l]  = pk2(vjx, vjy);
    xb[128 + l] = pk2(px, py);
  }
  __syncthreads();   // #1: broadcast rows + gather visible

  // ---- tokenlin m-split: wave rows [16w..+16), all 128 out cols
  {
    f32x4 acc[8];
    #pragma unroll
    for (int nt = 0; nt < 8; nt++) acc[nt] = zf;
    #pragma unroll
    for (int ks = 0; ks < 4; ks++){
      bf8 a = *(const bf8*)(sm + O_H + soff(w*16 + l15, ks*32 + lg*8, 256, 7));
      #pragma unroll
      for (int nt = 0; nt < 8; nt++){
        bf8 b = *(const bf8*)(wtok + ((nt*16 + ks)*64 + l)*8);
        acc[nt] = mfma16(a, b, acc[nt]);
      }
    }
    #pragma unroll
    for (int c = 1; c < 4; c++){
      #pragma unroll
      for (int ks = 0; ks < 4; ks++){
        bf8 a = *(const bf8*)(sm + O_RG + 512 + (e_w*192 + (c-1)*64)*4 + (ks*32 + lg*8)*2);
        #pragma unroll
        for (int nt = 0; nt < 8; nt++){
          bf8 b = *(const bf8*)(wtok + ((nt*16 + c*4 + ks)*64 + l)*8);
          acc[nt] = mfma16(a, b, acc[nt]);
        }
      }
    }
    #pragma unroll
    for (int nt = 0; nt < 8; nt++){
      int colg = nt*16 + l15;
      float tb = tok_b[colg];
      #pragma unroll
      for (int r = 0; r < 4; r++){
        int rowg = w*16 + lg*4 + r;
        float v = fmaxf(acc[nt][r] + tb, 0.f);
        *(u16*)(sm + O_TOK + soff(rowg, colg, 256, 7)) = f2bf(v);
      }
    }
  }
  // ---- LN1 (wave-private rows, no barrier)
  layernorm64(sm + O_TOK, sm + O_H, ln1_g, ln1_b, tid);
  __syncthreads();   // #2: H visible to edge-partner wave for qkv

  // ---- attention: wave = (edge e_w, heads hh_w*4..+4), fully private
  char* const qbuf = sm + O_RG + w*5120;
  char* const kbuf = qbuf + 1024;      // [32][32B]
  char* const vbuf = qbuf + 2048;      // VT [16][64B]
  char* const abuf = qbuf + 3072;      // ATT [32][64B]
  unsigned pkc[4][4];
  #pragma unroll
  for (int hi = 0; hi < 4; hi++){
    const int h = hh_w*4 + hi;
    f32x4 qa2[2] = {zf, zf}, ka2[2] = {zf, zf}, va2[2] = {zf, zf};
    #pragma unroll
    for (int ks = 0; ks < 4; ks++){
      bf8 a0 = *(const bf8*)(sm + O_H + soff(e_w*32 + l15,      ks*32 + lg*8, 256, 7));
      bf8 a1 = *(const bf8*)(sm + O_H + soff(e_w*32 + 16 + l15, ks*32 + lg*8, 256, 7));
      bf8 bq = *(const bf8*)(wqkv + ((( 0 + h)*4 + ks)*64 + l)*8);
      bf8 bk = *(const bf8*)(wqkv + ((( 8 + h)*4 + ks)*64 + l)*8);
      bf8 bv = *(const bf8*)(wqkv + (((16 + h)*4 + ks)*64 + l)*8);
      qa2[0] = mfma16(a0, bq, qa2[0]); qa2[1] = mfma16(a1, bq, qa2[1]);
      ka2[0] = mfma16(a0, bk, ka2[0]); ka2[1] = mfma16(a1, bk, ka2[1]);
      va2[0] = mfma16(a0, bv, va2[0]); va2[1] = mfma16(a1, bv, va2[1]);
    }
    float qbias = qkv_b[h*16 + l15];
    float kbias = qkv_b[128 + h*16 + l15];
    float vbias = qkv_b[256 + h*16 + l15];
    #pragma unroll
    for (int mt = 0; mt < 2; mt++){
      #pragma unroll
      for (int r = 0; r < 4; r++){
        int row = mt*16 + lg*4 + r;
        *(u16*)(qbuf + row*32 + l15*2) = f2bf(qa2[mt][r] + qbias);
        *(u16*)(kbuf + row*32 + l15*2) = f2bf(ka2[mt][r] + kbias);
        *(u16*)(vbuf + l15*64 + row*2) = f2bf(va2[mt][r] + vbias);
      }
    }
    // QK^T (dh=16 padded to K=32 via lg<2 mask)
    bf8 z8 = {0,0,0,0,0,0,0,0};
    bf8 qa[2], kf[2];
    #pragma unroll
    for (int mt = 0; mt < 2; mt++)
      qa[mt] = (lg < 2) ? *(const bf8*)(qbuf + (mt*16 + l15)*32 + lg*16) : z8;
    #pragma unroll
    for (int nt = 0; nt < 2; nt++)
      kf[nt] = (lg < 2) ? *(const bf8*)(kbuf + (nt*16 + l15)*32 + lg*16) : z8;
    f32x4 sc[2][2];
    #pragma unroll
    for (int mt = 0; mt < 2; mt++)
      #pragma unroll
      for (int nt = 0; nt < 2; nt++)
        sc[mt][nt] = mfma16(qa[mt], kf[nt], zf);
    float pr[2][2][4];
    #pragma unroll
    for (int mt = 0; mt < 2; mt++)
      #pragma unroll
      for (int nt = 0; nt < 2; nt++)
        #pragma unroll
        for (int r = 0; r < 4; r++)
          pr[mt][nt][r] = (nt*16 + l15 < cnt_e) ? sc[mt][nt][r]*0.25f : -1e9f;
    #pragma unroll
    for (int mt = 0; mt < 2; mt++)
      #pragma unroll
      for (int r = 0; r < 4; r++){
        float m = fmaxf(pr[mt][0][r], pr[mt][1][r]);
        m = fmaxf(m, __shfl_xor(m, 1)); m = fmaxf(m, __shfl_xor(m, 2));
        m = fmaxf(m, __shfl_xor(m, 4)); m = fmaxf(m, __shfl_xor(m, 8));
        float e0 = __expf(pr[mt][0][r] - m), e1 = __expf(pr[mt][1][r] - m);
        float ss = e0 + e1;
        ss += __shfl_xor(ss, 1); ss += __shfl_xor(ss, 2);
        ss += __shfl_xor(ss, 4); ss += __shfl_xor(ss, 8);
        float inv = 1.f / ss;
        int rowl = mt*16 + lg*4 + r;
        *(u16*)(abuf + rowl*64 + l15*2)      = f2bf(e0*inv);
        *(u16*)(abuf + rowl*64 + 32 + l15*2) = f2bf(e1*inv);
      }
    // PV
    bf8 vb = *(const bf8*)(vbuf + l15*64 + lg*16);
    #pragma unroll
    for (int mtp = 0; mtp < 2; mtp++){
      bf8 pa = *(const bf8*)(abuf + (mtp*16 + l15)*64 + lg*16);
      f32x4 cx = mfma16(pa, vb, zf);
      pkc[hi][mtp*2+0] = pk2(cx[0], cx[1]);
      pkc[hi][mtp*2+1] = pk2(cx[2], cx[3]);
    }
  }
  __syncthreads();   // #3: all private attn buffers dead

  // ---- write ctx to CTX region (overlays attn buffers)
  #pragma unroll
  for (int hi = 0; hi < 4; hi++){
    int head = hh_w*4 + hi;
    #pragma unroll
    for (int mtp = 0; mtp < 2; mtp++)
      #pragma unroll
      for (int i = 0; i < 2; i++){
        unsigned pv = pkc[hi][mtp*2+i];
        int rowg = e_w*32 + mtp*16 + lg*4 + i*2;
        *(u16*)(sm + O_RG + soff(rowg,     head*16 + l15, 256, 7)) = (u16)(pv & 0xffffu);
        *(u16*)(sm + O_RG + soff(rowg + 1, head*16 + l15, 256, 7)) = (u16)(pv >> 16);
      }
  }
  __syncthreads();   // #4: CTX complete

  // ---- out projection + residual (m-split, RMW own TOK rows)
  {
    f32x4 acc[8];
    #pragma unroll
    for (int nt = 0; nt < 8; nt++) acc[nt] = zf;
    #pragma unroll
    for (int ks = 0; ks < 4; ks++){
      bf8 a = *(const bf8*)(sm + O_RG + soff(w*16 + l15, ks*32 + lg*8, 256, 7));
      #pragma unroll
      for (int nt = 0; nt < 8; nt++){
        bf8 b = *(const bf8*)(wout + ((nt*4 + ks)*64 + l)*8);
        acc[nt] = mfma16(a, b, acc[nt]);
      }
    }
    #pragma unroll
    for (int nt = 0; nt < 8; nt++){
      int colg = nt*16 + l15;
      float ob = out_b[colg];
      #pragma unroll
      for (int r = 0; r < 4; r++){
        int rowg = w*16 + lg*4 + r;
        u16* tp = (u16*)(sm + O_TOK + soff(rowg, colg, 256, 7));
        float v = acc[nt][r] + ob + bf2f(*tp);
        *tp = f2bf(v);
      }
    }
  }
  // ---- LN2 (wave-private rows)
  layernorm64(sm + O_TOK, sm + O_H, ln2_g, ln2_b, tid);

  // ---- FF m-split, wave-private gelu buffer, no barriers
  char* const gb = sm + O_RG + w*4096;   // [16][256B] sw(256,7)
  f32x4 acc2[8];
  #pragma unroll
  for (int nt = 0; nt < 8; nt++) acc2[nt] = zf;
  #pragma unroll
  for (int c = 0; c < 4; c++){
    f32x4 acc1[8];
    #pragma unroll
    for (int nt = 0; nt < 8; nt++) acc1[nt] = zf;
    #pragma unroll
    for (int ks = 0; ks < 4; ks++){
      bf8 a = *(const bf8*)(sm + O_H + soff(w*16 + l15, ks*32 + lg*8, 256, 7));
      #pragma unroll
      for (int nt = 0; nt < 8; nt++){
        bf8 b = *(const bf8*)(wff1 + (((c*8 + nt)*4 + ks)*64 + l)*8);
        acc1[nt] = mfma16(a, b, acc1[nt]);
      }
    }
    #pragma unroll
    for (int nt = 0; nt < 8; nt++){
      float fb = ff1_b[c*128 + nt*16 + l15];
      #pragma unroll
      for (int r = 0; r < 4; r++){
        float vv = acc1[nt][r] + fb;
        vv = 0.5f*vv*(1.f + erff(vv*0.70710678118654752f));   // exact gelu
        *(u16*)(gb + soff(lg*4 + r, nt*16 + l15, 256, 7)) = f2bf(vv);
      }
    }
    #pragma unroll
    for (int ks = 0; ks < 4; ks++){
      bf8 a = *(const bf8*)(gb + soff(l15, ks*32 + lg*8, 256, 7));
      #pragma unroll
      for (int nt = 0; nt < 8; nt++){
        bf8 b = *(const bf8*)(wff2 + ((nt*16 + c*4 + ks)*64 + l)*8);
        acc2[nt] = mfma16(a, b, acc2[nt]);
      }
    }
  }

  // ---- final residual + masked pool (partials per wave -> own TOK region)
  {
    float p[8];
    #pragma unroll
    for (int nt = 0; nt < 8; nt++){
      int colg = nt*16 + l15;
      float fb = ff2_b[colg];
      float s = 0.f;
      #pragma unroll
      for (int r = 0; r < 4; r++){
        int rowg = w*16 + lg*4 + r;
        float tp = bf2f(*(u16*)(sm + O_TOK + soff(rowg, colg, 256, 7)));
        float v = acc2[nt][r] + fb + tp;
        if ((rowg & 31) < cnt_e) s += v;
      }
      p[nt] = s;
    }
    float* pbuf = (float*)(sm + O_TOK + w*4096);   // own rows' region, 512B used
    #pragma unroll
    for (int nt = 0; nt < 8; nt++){
      float s = p[nt];
      s += __shfl_xor(s, 16);
      s += __shfl_xor(s, 32);
      if (lg == 0) pbuf[nt*16 + l15] = s;
    }
  }
  __syncthreads();   // #5
  {
    int e = tid >> 7, col = tid & 127;
    float s = *(const float*)(sm + O_TOK + (e*2)*4096   + col*4)
            + *(const float*)(sm + O_TOK + (e*2+1)*4096 + col*4);
    int cn = cn_counts[t0 + e];
    float denom = (float)(cn > 0 ? cn : 1);
    xcn_out[(size_t)(t0 + e)*CC + col] = s / denom;
  }
}

// ------------------------------------------------------------------
// K2: edge MLPs, 16 edges/block, 512 blocks, 24KB LDS -> 6 blocks/CU.
// n-split (1 m-tile), same barrier pattern, 6x co-residency.
// ------------------------------------------------------------------
DI void gemm16(const char* sA, int astride, int ktiles, const u16* __restrict__ W,
               int w, int l, int l15, int lg, f32x4 (&acc)[4]){
  for (int ks = 0; ks < ktiles; ks++){
    bf8 a = *(const bf8*)(sA + soff(l15, ks*32 + lg*8, astride, 7));
    #pragma unroll
    for (int j = 0; j < 4; j++){
      bf8 b = *(const bf8*)(W + (((4*w + j)*ktiles + ks)*64 + l)*8);
      acc[j] = mfma16(a, b, acc[j]);
    }
  }
}

DI void store16(char* dst, f32x4 (&acc)[4], const float* __restrict__ bias, bool relu,
                int w, int l15, int lg){
  #pragma unroll
  for (int j = 0; j < 4; j++){
    int colg = (4*w + j)*16 + l15;
    float bb = bias[colg];
    #pragma unroll
    for (int r = 0; r < 4; r++){
      float v = acc[j][r] + bb;
      if (relu) v = fmaxf(v, 0.f);
      *(u16*)(dst + soff(lg*4 + r, colg, 512, 7)) = f2bf(v);
    }
  }
}

__global__ __launch_bounds__(256, 6)
void k2_mlp(const float* __restrict__ xcn, const float* __restrict__ xij,
            const u16* __restrict__ wbf,
            const float* __restrict__ xcn_b1, const float* __restrict__ xcn_b2,
            const float* __restrict__ xcn_b3, const float* __restrict__ xij_b1,
            const float* __restrict__ xij_b2, const float* __restrict__ lin_b1,
            const float* __restrict__ lin_w2, const float* __restrict__ lin_b2,
            const float* __restrict__ beta_p, float* __restrict__ out)
{
  __shared__ __align__(16) char sm[24576];
  const int O_A = 0, O_X = 4096, O_B1 = 8192, O_B2 = 16384;
  const u16* w1  = wbf + 262144;   // [256][128] frag-order
  const u16* w2  = wbf + 294912;   // [256][256]
  const u16* w3  = wbf + 360448;   // [256][256]
  const u16* xw1 = wbf + 425984;   // [256][128]
  const u16* xw2 = wbf + 458752;   // [256][256]
  const u16* lw1 = wbf + 524288;   // [256][256]
  const int tid = threadIdx.x;
  const int w = tid >> 6, l = tid & 63, l15 = l & 15, lg = (tid & 63) >> 4;
  const int t0 = blockIdx.x * 16;
  const f32x4 zf = {0.f,0.f,0.f,0.f};

  // stage xcn, xij as bf16 (16 rows, 16 threads/row, 8 floats each)
  {
    int r = tid >> 4, ci0 = (tid & 15) * 8;
    const float4* ps = (const float4*)(xcn + (size_t)(t0 + r)*CC + ci0);
    const float4* qs = (const float4*)(xij + (size_t)(t0 + r)*CC + ci0);
    float4 a = ps[0], b = ps[1];
    bf8 v;
    v[0]=(short)f2bf(a.x); v[1]=(short)f2bf(a.y); v[2]=(short)f2bf(a.z); v[3]=(short)f2bf(a.w);
    v[4]=(short)f2bf(b.x); v[5]=(short)f2bf(b.y); v[6]=(short)f2bf(b.z); v[7]=(short)f2bf(b.w);
    *(bf8*)(sm + O_A + soff(r, ci0, 256, 7)) = v;
    float4 cq = qs[0], dq = qs[1];
    bf8 u;
    u[0]=(short)f2bf(cq.x); u[1]=(short)f2bf(cq.y); u[2]=(short)f2bf(cq.z); u[3]=(short)f2bf(cq.w);
    u[4]=(short)f2bf(dq.x); u[5]=(short)f2bf(dq.y); u[6]=(short)f2bf(dq.z); u[7]=(short)f2bf(dq.w);
    *(bf8*)(sm + O_X + soff(r, ci0, 256, 7)) = u;
  }
  __syncthreads();

  f32x4 acc[4];
  // L1: relu(xcn @ w1^T + b1) : A -> B1
  #pragma unroll
  for (int j=0;j<4;j++) acc[j] = zf;
  gemm16(sm + O_A, 256, 4, w1, w, l, l15, lg, acc);
  store16(sm + O_B1, acc, xcn_b1, true, w, l15, lg);
  __syncthreads();
  // L2: relu(h1 @ w2^T + b2) : B1 -> B2
  #pragma unroll
  for (int j=0;j<4;j++) acc[j] = zf;
  gemm16(sm + O_B1, 512, 8, w2, w, l, l15, lg, acc);
  store16(sm + O_B2, acc, xcn_b2, true, w, l15, lg);
  __syncthreads();
  // L3 (no act) B2 -> regs; X1: X -> B1
  f32x4 hc[4];
  #pragma unroll
  for (int j=0;j<4;j++) hc[j] = zf;
  gemm16(sm + O_B2, 512, 8, w3, w, l, l15, lg, hc);
  #pragma unroll
  for (int j=0;j<4;j++) acc[j] = zf;
  gemm16(sm + O_X, 256, 4, xw1, w, l, l15, lg, acc);
  store16(sm + O_B1, acc, xij_b1, true, w, l15, lg);
  __syncthreads();
  // X2 (no act): B1 -> regs; combine -> B2
  f32x4 x2[4];
  #pragma unroll
  for (int j=0;j<4;j++) x2[j] = zf;
  gemm16(sm + O_B1, 512, 8, xw2, w, l, l15, lg, x2);
  {
    float beta = beta_p[0];
    #pragma unroll
    for (int j = 0; j < 4; j++){
      int colg = (4*w + j)*16 + l15;
      float b3v = xcn_b3[colg], xbv = xij_b2[colg];
      #pragma unroll
      for (int r = 0; r < 4; r++){
        float v = (hc[j][r] + b3v)*beta + (x2[j][r] + xbv);
        *(u16*)(sm + O_B2 + soff(lg*4 + r, colg, 512, 7)) = f2bf(v);
      }
    }
  }
  __syncthreads();
  // Z: relu(z0 @ lin_w1^T + lin_b1) : B2 -> B1
  #pragma unroll
  for (int j=0;j<4;j++) acc[j] = zf;
  gemm16(sm + O_B2, 512, 8, lw1, w, l, l15, lg, acc);
  store16(sm + O_B1, acc, lin_b1, true, w, l15, lg);
  __syncthreads();
  // final dot with lin_w2 (16 lanes per edge)
  {
    int e = tid >> 4, li = tid & 15;
    float s = 0.f;
    #pragma unroll
    for (int i = 0; i < 16; i++){
      int c = li*16 + i;
      s += bf2f(*(u16*)(sm + O_B1 + soff(e, c, 512, 7))) * lin_w2[c];
    }
    s += __shfl_xor(s, 1); s += __shfl_xor(s, 2);
    s += __shfl_xor(s, 4); s += __shfl_xor(s, 8);
    if (li == 0) out[t0 + e] = s + lin_b2[0];
  }
}

// ------------------------------------------------------------------
extern "C" void kernel_launch(void* const* d_in, const int* in_sizes, int n_in,
                              void* d_out, int out_size, void* d_ws, size_t ws_size,
                              hipStream_t stream){
  (void)in_sizes; (void)n_in; (void)out_size; (void)ws_size;
  const float* x        = (const float*)d_in[0];
  const int*   tar_ei   = (const int*)  d_in[1];
  const int*   cn_cols  = (const int*)  d_in[2];
  const int*   cn_cnt   = (const int*)  d_in[3];
  const float* beta     = (const float*)d_in[4];
  const float* tok_w    = (const float*)d_in[5];
  const float* tok_b    = (const float*)d_in[6];
  const float* ln1_g    = (const float*)d_in[7];
  const float* ln1_b    = (const float*)d_in[8];
  const float* qkv_w    = (const float*)d_in[9];
  const float* qkv_b    = (const float*)d_in[10];
  const float* out_w    = (const float*)d_in[11];
  const float* out_b    = (const float*)d_in[12];
  const float* ln2_g    = (const float*)d_in[13];
  const float* ln2_b    = (const float*)d_in[14];
  const float* ff1_w    = (const float*)d_in[15];
  const float* ff1_b    = (const float*)d_in[16];
  const float* ff2_w    = (const float*)d_in[17];
  const float* ff2_b    = (const float*)d_in[18];
  const float* xcn_w1   = (const float*)d_in[19];
  const float* xcn_b1   = (const float*)d_in[20];
  const float* xcn_w2   = (const float*)d_in[21];
  const float* xcn_b2   = (const float*)d_in[22];
  const float* xcn_w3   = (const float*)d_in[23];
  const float* xcn_b3   = (const float*)d_in[24];
  const float* xij_w1   = (const float*)d_in[25];
  const float* xij_b1   = (const float*)d_in[26];
  const float* xij_w2   = (const float*)d_in[27];
  const float* xij_b2   = (const float*)d_in[28];
  const float* lin_w1   = (const float*)d_in[29];
  const float* lin_b1   = (const float*)d_in[30];
  const float* lin_w2   = (const float*)d_in[31];
  const float* lin_b2   = (const float*)d_in[32];

  u16*   wbf = (u16*)d_ws;
  float* xcn = (float*)((char*)d_ws + (size_t)(2u<<20));   // 4 MB
  float* xij = (float*)((char*)d_ws + (size_t)(6u<<20));   // 4 MB

  WP wp;
  wp.p[0]=tok_w; wp.p[1]=qkv_w; wp.p[2]=out_w; wp.p[3]=ff1_w; wp.p[4]=ff2_w;
  wp.p[5]=xcn_w1; wp.p[6]=xcn_w2; wp.p[7]=xcn_w3; wp.p[8]=xij_w1; wp.p[9]=xij_w2;
  wp.p[10]=lin_w1; wp.p[11]=lin_w2;

  k0_convert<<<dim3(2305), dim3(256), 0, stream>>>(wp, wbf);
  k1_fused<<<dim3(TT/2), dim3(256), 0, stream>>>(
      x, tar_ei, cn_cols, cn_cnt, tok_b, ln1_g, ln1_b, qkv_b, out_b,
      ln2_g, ln2_b, ff1_b, ff2_b, wbf, xcn, xij);
  k2_mlp<<<dim3(TT/16), dim3(256), 0, stream>>>(
      xcn, xij, wbf, xcn_b1, xcn_b2, xcn_b3, xij_b1, xij_b2,
      lin_b1, lin_w2, lin_b2, beta, (float*)d_out);
}

// Round 5
// 548.361 us; speedup vs baseline: 1.8360x; 1.8360x over previous
//
#include <hip/hip_runtime.h>
#include <hip/hip_bf16.h>
#include <math.h>

#define DI __device__ __forceinline__

typedef float  f32x4 __attribute__((ext_vector_type(4)));
typedef short  bf8   __attribute__((ext_vector_type(8)));
typedef unsigned short u16;

static constexpr int TT = 8192;   // T edges
static constexpr int KK = 32;     // CN tokens per edge
static constexpr int CC = 128;    // channels

DI u16 f2bf(float x){ union{float f; unsigned u;} v; v.f = x; unsigned r = v.u + 0x7FFFu + ((v.u>>16)&1u); return (u16)(r>>16); }
DI float bf2f(u16 b){ union{unsigned u; float f;} v; v.u = ((unsigned)b)<<16; return v.f; }
DI unsigned pk2(float a, float b){ return (unsigned)f2bf(a) | ((unsigned)f2bf(b)<<16); }
DI f32x4 mfma16(bf8 a, bf8 b, f32x4 c){ return __builtin_amdgcn_mfma_f32_16x16x32_bf16(a, b, c, 0, 0, 0); }
// swizzled LDS byte offset: row-major [*][stride bytes], xor row bits into 16B-slot bits
DI int soff(int r, int c, int stride, int mask){ return r*stride + ((c*2) ^ ((r&mask)<<4)); }

// ------------------------------------------------------------------
// K0: convert weights fp32 -> bf16 blob in MFMA fragment order:
//   W'[((n16*(K/32) + k32)*64 + l)*8 + e] = W[n16*16 + (l&15)][k32*32 + (l>>4)*8 + e]
// ------------------------------------------------------------------
struct WP { const float* p[12]; };

__global__ void k0_convert(WP wp, u16* __restrict__ dst){
  const int KS[11]  = {512,128,128,128,512,128,256,256,128,256,256};
  const int SH[11]  = {4,2,2,2,4,2,3,3,2,3,3};   // log2(K/32)
  const int OFF[12] = {0,65536,114688,131072,196608,262144,294912,360448,425984,458752,524288,589824};
  int gid = blockIdx.x*256 + threadIdx.x;        // 2305*256 = 590080
  if (gid >= 590080) return;
  if (gid >= 589824){ dst[gid] = f2bf(wp.p[11][gid - 589824]); return; }   // lin_w2 linear
  #pragma unroll
  for (int s = 0; s < 11; s++){
    if (gid < OFF[s+1]){
      int i = gid - OFF[s];
      int e = i & 7, l = (i >> 3) & 63, t = i >> 9;
      int k32 = t & ((1 << SH[s]) - 1), n16 = t >> SH[s];
      int row = n16*16 + (l & 15);
      int col = k32*32 + ((l >> 4) << 3) + e;
      dst[gid] = f2bf(wp.p[s][row*KS[s] + col]);
      return;
    }
  }
}

// ------------------------------------------------------------------
// K1: fused, n-split over 8 waves (512 threads), 2 edges/block.
// Wave w owns output cols [16w,16w+16) in every GEMM (weights read once/block).
// Attention: wave = (edge w>>2, head-sub (w>>1)&1, row-half w&1).
// LDS 52K -> 3 blocks/CU = 6 waves/SIMD.
// ------------------------------------------------------------------
#define O_TOK 0        // [64][128] bf16 sw(256,7) 16K residual
#define O_H   16384    // [64][128] bf16 sw(256,7) 16K ln out / xw staging
#define O_RG  32768    // 20480B multi-use:
                       //  phase0: xibuf u32[2][3][64] @+512
                       //  attn:   Q[64][32] sw(64,3) @0, K @4096, VT[32][64] sw(128,7) @8192,
                       //          ATT 4x(32x32) @12288
                       //  ctx / gelu chunk: [64][128] sw(256,7) @0 (16K)
#define LDS_K1 53248

DI void layernorm64(const char* src, char* dst, const float* __restrict__ g,
                    const float* __restrict__ bta, int tid){
  int r = tid >> 3, q = tid & 7;
  float v[16]; float s = 0.f, sq = 0.f;
  #pragma unroll
  for (int i = 0; i < 2; i++){
    bf8 h8 = *(const bf8*)(src + soff(r, q*16 + i*8, 256, 7));
    #pragma unroll
    for (int j = 0; j < 8; j++){ float f = bf2f((u16)h8[j]); v[i*8+j] = f; s += f; sq += f*f; }
  }
  s  += __shfl_xor(s, 1);  s  += __shfl_xor(s, 2);  s  += __shfl_xor(s, 4);
  sq += __shfl_xor(sq, 1); sq += __shfl_xor(sq, 2); sq += __shfl_xor(sq, 4);
  float mu = s * (1.f/128.f);
  float rstd = rsqrtf(sq*(1.f/128.f) - mu*mu + 1e-5f);
  #pragma unroll
  for (int i = 0; i < 2; i++){
    bf8 o;
    #pragma unroll
    for (int j = 0; j < 8; j++){
      int c = q*16 + i*8 + j;
      o[j] = (short)f2bf((v[i*8+j] - mu)*rstd*g[c] + bta[c]);
    }
    *(bf8*)(dst + soff(r, q*16 + i*8, 256, 7)) = o;
  }
}

__global__ __launch_bounds__(512, 6)
void k1_fused(const float* __restrict__ x, const int* __restrict__ tar_ei,
              const int* __restrict__ cn_cols, const int* __restrict__ cn_counts,
              const float* __restrict__ tok_b,
              const float* __restrict__ ln1_g, const float* __restrict__ ln1_b,
              const float* __restrict__ qkv_b, const float* __restrict__ out_b,
              const float* __restrict__ ln2_g, const float* __restrict__ ln2_b,
              const float* __restrict__ ff1_b, const float* __restrict__ ff2_b,
              const u16* __restrict__ wbf,
              float* __restrict__ xcn_out, float* __restrict__ xij_out)
{
  __shared__ __align__(16) char sm[LDS_K1];
  const int tid = threadIdx.x;
  const int w = tid >> 6, l = tid & 63, l15 = l & 15, lg = l >> 4;
  const int t0 = blockIdx.x * 2;

  const u16* wtok = wbf;            // [128][512] frag-order
  const u16* wqkv = wbf + 65536;    // [384][128]
  const u16* wout = wbf + 114688;   // [128][128]
  const u16* wff1 = wbf + 131072;   // [512][128]
  const u16* wff2 = wbf + 196608;   // [128][512]

  const f32x4 zf = {0.f, 0.f, 0.f, 0.f};
  const int cnt0 = cn_counts[t0], cnt1 = cn_counts[t0 + 1];
  const int colg = w*16 + l15;      // n-split column for GEMM epilogues

  // ---- phase 0a: gather xw -> sH. 8 threads per row, 16 floats each.
  {
    int r = tid >> 3, q = tid & 7;
    int col = cn_cols[(t0 + (r >> 5))*KK + (r & 31)];
    const float4* xs = (const float4*)(x + (size_t)col*CC) + q*4;
    #pragma unroll
    for (int i = 0; i < 2; i++){
      float4 a = xs[2*i], b = xs[2*i+1];
      bf8 v;
      v[0]=(short)f2bf(a.x); v[1]=(short)f2bf(a.y); v[2]=(short)f2bf(a.z); v[3]=(short)f2bf(a.w);
      v[4]=(short)f2bf(b.x); v[5]=(short)f2bf(b.y); v[6]=(short)f2bf(b.z); v[7]=(short)f2bf(b.w);
      *(bf8*)(sm + O_H + soff(r, q*16 + i*8, 256, 7)) = v;
    }
  }
  // ---- phase 0b: stage xi/xj/xi*xj broadcast rows + write xij (waves 0-1)
  if (w < 2){
    int e = w, c0 = l*2;
    int ti = tar_ei[t0 + e], tj = tar_ei[TT + t0 + e];
    float vix = x[(size_t)ti*CC + c0], viy = x[(size_t)ti*CC + c0 + 1];
    float vjx = x[(size_t)tj*CC + c0], vjy = x[(size_t)tj*CC + c0 + 1];
    float px = vix*vjx, py = viy*vjy;
    xij_out[(size_t)(t0+e)*CC + c0]     = px;
    xij_out[(size_t)(t0+e)*CC + c0 + 1] = py;
    unsigned* xb = (unsigned*)(sm + O_RG + 512) + e*192;   // [3][64] u32
    xb[l]       = pk2(vix, viy);
    xb[64 + l]  = pk2(vjx, vjy);
    xb[128 + l] = pk2(px, py);
  }
  __syncthreads();   // #1

  // ---- tokenlin: n-split; broadcast chunks use identical-row trick (accB)
  {
    f32x4 acc[4], accB[2];
    #pragma unroll
    for (int mt = 0; mt < 4; mt++) acc[mt] = zf;
    accB[0] = zf; accB[1] = zf;
    #pragma unroll
    for (int ks = 0; ks < 4; ks++){
      bf8 b = *(const bf8*)(wtok + ((w*16 + ks)*64 + l)*8);
      #pragma unroll
      for (int mt = 0; mt < 4; mt++){
        bf8 a = *(const bf8*)(sm + O_H + soff(mt*16 + l15, ks*32 + lg*8, 256, 7));
        acc[mt] = mfma16(a, b, acc[mt]);
      }
    }
    #pragma unroll
    for (int c = 1; c < 4; c++){
      #pragma unroll
      for (int ks = 0; ks < 4; ks++){
        bf8 b  = *(const bf8*)(wtok + ((w*16 + c*4 + ks)*64 + l)*8);
        bf8 a0 = *(const bf8*)(sm + O_RG + 512 + 0*768 + (c-1)*256 + (ks*32 + lg*8)*2);
        bf8 a1 = *(const bf8*)(sm + O_RG + 512 + 1*768 + (c-1)*256 + (ks*32 + lg*8)*2);
        accB[0] = mfma16(a0, b, accB[0]);
        accB[1] = mfma16(a1, b, accB[1]);
      }
    }
    float tb = tok_b[colg];
    #pragma unroll
    for (int mt = 0; mt < 4; mt++){
      #pragma unroll
      for (int r = 0; r < 4; r++){
        int rowg = mt*16 + lg*4 + r;
        float v = fmaxf(acc[mt][r] + accB[mt>>1][r] + tb, 0.f);
        *(u16*)(sm + O_TOK + soff(rowg, colg, 256, 7)) = f2bf(v);
      }
    }
  }
  __syncthreads();   // #2

  // ---- LN1: sTok -> sH
  layernorm64(sm + O_TOK, sm + O_H, ln1_g, ln1_b, tid);
  __syncthreads();   // #3

  // ---- attention: 4 chunks of 2 heads, 8 waves fully employed
  const int e_w = w >> 2, hs_w = (w >> 1) & 1, hf_w = w & 1;
  const int cnt_e = (e_w == 0) ? cnt0 : cnt1;
  char* const sQ  = sm + O_RG;
  char* const sK  = sm + O_RG + 4096;
  char* const sVT = sm + O_RG + 8192;
  char* const sAT = sm + O_RG + 12288 + (e_w*2 + hs_w)*2048;
  unsigned pkc[4][2];
  #pragma unroll
  for (int hc2 = 0; hc2 < 4; hc2++){
    // qkv: waves 0-3 do q/k (full 64 rows); waves 4-7 do v half-tiles
    if (w < 4){
      int kind = w >> 1, sub = w & 1;
      int n16 = kind*8 + hc2*2 + sub;
      f32x4 acc[4];
      #pragma unroll
      for (int mt = 0; mt < 4; mt++) acc[mt] = zf;
      #pragma unroll
      for (int ks = 0; ks < 4; ks++){
        bf8 b = *(const bf8*)(wqkv + ((n16*4 + ks)*64 + l)*8);
        #pragma unroll
        for (int mt = 0; mt < 4; mt++){
          bf8 a = *(const bf8*)(sm + O_H + soff(mt*16 + l15, ks*32 + lg*8, 256, 7));
          acc[mt] = mfma16(a, b, acc[mt]);
        }
      }
      float bias = qkv_b[n16*16 + l15];
      char* dst = (kind == 0) ? sQ : sK;
      #pragma unroll
      for (int mt = 0; mt < 4; mt++)
        #pragma unroll
        for (int r = 0; r < 4; r++){
          int rowg = mt*16 + lg*4 + r;
          *(u16*)(dst + soff(rowg, sub*16 + l15, 64, 3)) = f2bf(acc[mt][r] + bias);
        }
    } else {
      int sub = (w >> 1) & 1, half = w & 1;
      int n16 = 16 + hc2*2 + sub;
      f32x4 acc[2];
      acc[0] = zf; acc[1] = zf;
      #pragma unroll
      for (int ks = 0; ks < 4; ks++){
        bf8 b = *(const bf8*)(wqkv + ((n16*4 + ks)*64 + l)*8);
        #pragma unroll
        for (int m = 0; m < 2; m++){
          bf8 a = *(const bf8*)(sm + O_H + soff((half*2 + m)*16 + l15, ks*32 + lg*8, 256, 7));
          acc[m] = mfma16(a, b, acc[m]);
        }
      }
      float bias = qkv_b[n16*16 + l15];
      #pragma unroll
      for (int m = 0; m < 2; m++)
        #pragma unroll
        for (int r = 0; r < 4; r++){
          int rowg = (half*2 + m)*16 + lg*4 + r;
          *(u16*)(sVT + soff(sub*16 + l15, rowg, 128, 7)) = f2bf(acc[m][r] + bias);
        }
    }
    __syncthreads();

    // per-wave attention: (edge e_w, head-sub hs_w, row-half hf_w)
    {
      bf8 z8 = {0,0,0,0,0,0,0,0};
      bf8 qa = (lg < 2) ? *(const bf8*)(sQ + soff(e_w*32 + hf_w*16 + l15, hs_w*16 + lg*8, 64, 3)) : z8;
      bf8 kb[2];
      #pragma unroll
      for (int nt = 0; nt < 2; nt++)
        kb[nt] = (lg < 2) ? *(const bf8*)(sK + soff(e_w*32 + nt*16 + l15, hs_w*16 + lg*8, 64, 3)) : z8;
      f32x4 sc[2];
      sc[0] = mfma16(qa, kb[0], zf);
      sc[1] = mfma16(qa, kb[1], zf);
      float pr[2][4];
      #pragma unroll
      for (int nt = 0; nt < 2; nt++)
        #pragma unroll
        for (int r = 0; r < 4; r++)
          pr[nt][r] = (nt*16 + l15 < cnt_e) ? sc[nt][r]*0.25f : -1e9f;
      #pragma unroll
      for (int r = 0; r < 4; r++){
        float m = fmaxf(pr[0][r], pr[1][r]);
        m = fmaxf(m, __shfl_xor(m, 1)); m = fmaxf(m, __shfl_xor(m, 2));
        m = fmaxf(m, __shfl_xor(m, 4)); m = fmaxf(m, __shfl_xor(m, 8));
        float e0 = __expf(pr[0][r] - m), e1 = __expf(pr[1][r] - m);
        float ss = e0 + e1;
        ss += __shfl_xor(ss, 1); ss += __shfl_xor(ss, 2);
        ss += __shfl_xor(ss, 4); ss += __shfl_xor(ss, 8);
        float inv = 1.f / ss;
        int rowl = hf_w*16 + lg*4 + r;
        *(u16*)(sAT + soff(rowl, l15,      64, 3)) = f2bf(e0*inv);
        *(u16*)(sAT + soff(rowl, 16 + l15, 64, 3)) = f2bf(e1*inv);
      }
      // PV (reads only this wave's rows; same-wave DS ordering)
      bf8 vb = *(const bf8*)(sVT + soff(hs_w*16 + l15, e_w*32 + lg*8, 128, 7));
      bf8 pa = *(const bf8*)(sAT + soff(hf_w*16 + l15, lg*8, 64, 3));
      f32x4 cx = mfma16(pa, vb, zf);
      pkc[hc2][0] = pk2(cx[0], cx[1]);
      pkc[hc2][1] = pk2(cx[2], cx[3]);
    }
    __syncthreads();
  }

  // ---- write ctx to CTX region (overlays attn buffers)
  #pragma unroll
  for (int hc = 0; hc < 4; hc++){
    int head = hc*2 + hs_w;
    int rowbase = e_w*32 + hf_w*16 + lg*4;
    #pragma unroll
    for (int i = 0; i < 2; i++){
      unsigned pv = pkc[hc][i];
      *(u16*)(sm + O_RG + soff(rowbase + i*2,     head*16 + l15, 256, 7)) = (u16)(pv & 0xffffu);
      *(u16*)(sm + O_RG + soff(rowbase + i*2 + 1, head*16 + l15, 256, 7)) = (u16)(pv >> 16);
    }
  }
  __syncthreads();   // ctx complete

  // ---- out projection + residual (n-split, RMW own TOK cols)
  {
    f32x4 acc[4];
    #pragma unroll
    for (int mt = 0; mt < 4; mt++) acc[mt] = zf;
    #pragma unroll
    for (int ks = 0; ks < 4; ks++){
      bf8 b = *(const bf8*)(wout + ((w*4 + ks)*64 + l)*8);
      #pragma unroll
      for (int mt = 0; mt < 4; mt++){
        bf8 a = *(const bf8*)(sm + O_RG + soff(mt*16 + l15, ks*32 + lg*8, 256, 7));
        acc[mt] = mfma16(a, b, acc[mt]);
      }
    }
    float ob = out_b[colg];
    #pragma unroll
    for (int mt = 0; mt < 4; mt++)
      #pragma unroll
      for (int r = 0; r < 4; r++){
        int rowg = mt*16 + lg*4 + r;
        u16* tp = (u16*)(sm + O_TOK + soff(rowg, colg, 256, 7));
        float v = acc[mt][r] + ob + bf2f(*tp);
        *tp = f2bf(v);
      }
  }
  __syncthreads();

  // ---- LN2: sTok -> sH
  layernorm64(sm + O_TOK, sm + O_H, ln2_g, ln2_b, tid);
  __syncthreads();

  // ---- FF: 4 column chunks of 128; n-split; fp32 acc carried across chunks
  f32x4 acc2[4];
  #pragma unroll
  for (int mt = 0; mt < 4; mt++) acc2[mt] = zf;
  for (int c = 0; c < 4; c++){
    f32x4 acc1[4];
    #pragma unroll
    for (int mt = 0; mt < 4; mt++) acc1[mt] = zf;
    #pragma unroll
    for (int ks = 0; ks < 4; ks++){
      bf8 b = *(const bf8*)(wff1 + (((c*8 + w)*4 + ks)*64 + l)*8);
      #pragma unroll
      for (int mt = 0; mt < 4; mt++){
        bf8 a = *(const bf8*)(sm + O_H + soff(mt*16 + l15, ks*32 + lg*8, 256, 7));
        acc1[mt] = mfma16(a, b, acc1[mt]);
      }
    }
    float fb = ff1_b[c*128 + colg];
    #pragma unroll
    for (int mt = 0; mt < 4; mt++)
      #pragma unroll
      for (int r = 0; r < 4; r++){
        int rowg = mt*16 + lg*4 + r;
        float vv = acc1[mt][r] + fb;
        vv = 0.5f*vv*(1.f + erff(vv*0.70710678118654752f));   // exact gelu
        *(u16*)(sm + O_RG + soff(rowg, colg, 256, 7)) = f2bf(vv);
      }
    __syncthreads();
    #pragma unroll
    for (int ks = 0; ks < 4; ks++){
      bf8 b = *(const bf8*)(wff2 + ((w*16 + c*4 + ks)*64 + l)*8);
      #pragma unroll
      for (int mt = 0; mt < 4; mt++){
        bf8 a = *(const bf8*)(sm + O_RG + soff(mt*16 + l15, ks*32 + lg*8, 256, 7));
        acc2[mt] = mfma16(a, b, acc2[mt]);
      }
    }
    __syncthreads();
  }

  // ---- final residual + masked mean pool (no LDS round-trip)
  {
    float pool[2] = {0.f, 0.f};
    float fb = ff2_b[colg];
    #pragma unroll
    for (int mt = 0; mt < 4; mt++){
      int cnt_m = (mt < 2) ? cnt0 : cnt1;
      #pragma unroll
      for (int r = 0; r < 4; r++){
        int rowg = mt*16 + lg*4 + r;
        float tp = bf2f(*(u16*)(sm + O_TOK + soff(rowg, colg, 256, 7)));
        float v = acc2[mt][r] + fb + tp;
        if ((rowg & 31) < cnt_m) pool[mt >> 1] += v;
      }
    }
    #pragma unroll
    for (int e = 0; e < 2; e++){
      float v = pool[e];
      v += __shfl_xor(v, 16);
      v += __shfl_xor(v, 32);
      if (lg == 0){
        int cn = (e == 0) ? cnt0 : cnt1;
        float denom = (float)(cn > 0 ? cn : 1);
        xcn_out[(size_t)(t0 + e)*CC + colg] = v / denom;
      }
    }
  }
}

// ------------------------------------------------------------------
// K2: edge MLPs, 16 edges/block, 512 blocks, 24KB LDS -> 6 blocks/CU.
// ------------------------------------------------------------------
DI void gemm16(const char* sA, int astride, int ktiles, const u16* __restrict__ W,
               int w, int l, int l15, int lg, f32x4 (&acc)[4]){
  for (int ks = 0; ks < ktiles; ks++){
    bf8 a = *(const bf8*)(sA + soff(l15, ks*32 + lg*8, astride, 7));
    #pragma unroll
    for (int j = 0; j < 4; j++){
      bf8 b = *(const bf8*)(W + (((4*w + j)*ktiles + ks)*64 + l)*8);
      acc[j] = mfma16(a, b, acc[j]);
    }
  }
}

DI void store16(char* dst, f32x4 (&acc)[4], const float* __restrict__ bias, bool relu,
                int w, int l15, int lg){
  #pragma unroll
  for (int j = 0; j < 4; j++){
    int colg = (4*w + j)*16 + l15;
    float bb = bias[colg];
    #pragma unroll
    for (int r = 0; r < 4; r++){
      float v = acc[j][r] + bb;
      if (relu) v = fmaxf(v, 0.f);
      *(u16*)(dst + soff(lg*4 + r, colg, 512, 7)) = f2bf(v);
    }
  }
}

__global__ __launch_bounds__(256, 6)
void k2_mlp(const float* __restrict__ xcn, const float* __restrict__ xij,
            const u16* __restrict__ wbf,
            const float* __restrict__ xcn_b1, const float* __restrict__ xcn_b2,
            const float* __restrict__ xcn_b3, const float* __restrict__ xij_b1,
            const float* __restrict__ xij_b2, const float* __restrict__ lin_b1,
            const float* __restrict__ lin_w2, const float* __restrict__ lin_b2,
            const float* __restrict__ beta_p, float* __restrict__ out)
{
  __shared__ __align__(16) char sm[24576];
  const int O_A = 0, O_X = 4096, O_B1 = 8192, O_B2 = 16384;
  const u16* w1  = wbf + 262144;   // [256][128] frag-order
  const u16* w2  = wbf + 294912;   // [256][256]
  const u16* w3  = wbf + 360448;   // [256][256]
  const u16* xw1 = wbf + 425984;   // [256][128]
  const u16* xw2 = wbf + 458752;   // [256][256]
  const u16* lw1 = wbf + 524288;   // [256][256]
  const int tid = threadIdx.x;
  const int w = tid >> 6, l = tid & 63, l15 = l & 15, lg = (tid & 63) >> 4;
  const int t0 = blockIdx.x * 16;
  const f32x4 zf = {0.f,0.f,0.f,0.f};

  // stage xcn, xij as bf16 (16 rows, 16 threads/row, 8 floats each)
  {
    int r = tid >> 4, ci0 = (tid & 15) * 8;
    const float4* ps = (const float4*)(xcn + (size_t)(t0 + r)*CC + ci0);
    const float4* qs = (const float4*)(xij + (size_t)(t0 + r)*CC + ci0);
    float4 a = ps[0], b = ps[1];
    bf8 v;
    v[0]=(short)f2bf(a.x); v[1]=(short)f2bf(a.y); v[2]=(short)f2bf(a.z); v[3]=(short)f2bf(a.w);
    v[4]=(short)f2bf(b.x); v[5]=(short)f2bf(b.y); v[6]=(short)f2bf(b.z); v[7]=(short)f2bf(b.w);
    *(bf8*)(sm + O_A + soff(r, ci0, 256, 7)) = v;
    float4 cq = qs[0], dq = qs[1];
    bf8 u;
    u[0]=(short)f2bf(cq.x); u[1]=(short)f2bf(cq.y); u[2]=(short)f2bf(cq.z); u[3]=(short)f2bf(cq.w);
    u[4]=(short)f2bf(dq.x); u[5]=(short)f2bf(dq.y); u[6]=(short)f2bf(dq.z); u[7]=(short)f2bf(dq.w);
    *(bf8*)(sm + O_X + soff(r, ci0, 256, 7)) = u;
  }
  __syncthreads();

  f32x4 acc[4];
  // L1: relu(xcn @ w1^T + b1) : A -> B1
  #pragma unroll
  for (int j=0;j<4;j++) acc[j] = zf;
  gemm16(sm + O_A, 256, 4, w1, w, l, l15, lg, acc);
  store16(sm + O_B1, acc, xcn_b1, true, w, l15, lg);
  __syncthreads();
  // L2: relu(h1 @ w2^T + b2) : B1 -> B2
  #pragma unroll
  for (int j=0;j<4;j++) acc[j] = zf;
  gemm16(sm + O_B1, 512, 8, w2, w, l, l15, lg, acc);
  store16(sm + O_B2, acc, xcn_b2, true, w, l15, lg);
  __syncthreads();
  // L3 (no act) B2 -> regs; X1: X -> B1
  f32x4 hc[4];
  #pragma unroll
  for (int j=0;j<4;j++) hc[j] = zf;
  gemm16(sm + O_B2, 512, 8, w3, w, l, l15, lg, hc);
  #pragma unroll
  for (int j=0;j<4;j++) acc[j] = zf;
  gemm16(sm + O_X, 256, 4, xw1, w, l, l15, lg, acc);
  store16(sm + O_B1, acc, xij_b1, true, w, l15, lg);
  __syncthreads();
  // X2 (no act): B1 -> regs; combine -> B2
  f32x4 x2[4];
  #pragma unroll
  for (int j=0;j<4;j++) x2[j] = zf;
  gemm16(sm + O_B1, 512, 8, xw2, w, l, l15, lg, x2);
  {
    float beta = beta_p[0];
    #pragma unroll
    for (int j = 0; j < 4; j++){
      int colg = (4*w + j)*16 + l15;
      float b3v = xcn_b3[colg], xbv = xij_b2[colg];
      #pragma unroll
      for (int r = 0; r < 4; r++){
        float v = (hc[j][r] + b3v)*beta + (x2[j][r] + xbv);
        *(u16*)(sm + O_B2 + soff(lg*4 + r, colg, 512, 7)) = f2bf(v);
      }
    }
  }
  __syncthreads();
  // Z: relu(z0 @ lin_w1^T + lin_b1) : B2 -> B1
  #pragma unroll
  for (int j=0;j<4;j++) acc[j] = zf;
  gemm16(sm + O_B2, 512, 8, lw1, w, l, l15, lg, acc);
  store16(sm + O_B1, acc, lin_b1, true, w, l15, lg);
  __syncthreads();
  // final dot with lin_w2 (16 lanes per edge)
  {
    int e = tid >> 4, li = tid & 15;
    float s = 0.f;
    #pragma unroll
    for (int i = 0; i < 16; i++){
      int c = li*16 + i;
      s += bf2f(*(u16*)(sm + O_B1 + soff(e, c, 512, 7))) * lin_w2[c];
    }
    s += __shfl_xor(s, 1); s += __shfl_xor(s, 2);
    s += __shfl_xor(s, 4); s += __shfl_xor(s, 8);
    if (li == 0) out[t0 + e] = s + lin_b2[0];
  }
}

// ------------------------------------------------------------------
extern "C" void kernel_launch(void* const* d_in, const int* in_sizes, int n_in,
                              void* d_out, int out_size, void* d_ws, size_t ws_size,
                              hipStream_t stream){
  (void)in_sizes; (void)n_in; (void)out_size; (void)ws_size;
  const float* x        = (const float*)d_in[0];
  const int*   tar_ei   = (const int*)  d_in[1];
  const int*   cn_cols  = (const int*)  d_in[2];
  const int*   cn_cnt   = (const int*)  d_in[3];
  const float* beta     = (const float*)d_in[4];
  const float* tok_w    = (const float*)d_in[5];
  const float* tok_b    = (const float*)d_in[6];
  const float* ln1_g    = (const float*)d_in[7];
  const float* ln1_b    = (const float*)d_in[8];
  const float* qkv_w    = (const float*)d_in[9];
  const float* qkv_b    = (const float*)d_in[10];
  const float* out_w    = (const float*)d_in[11];
  const float* out_b    = (const float*)d_in[12];
  const float* ln2_g    = (const float*)d_in[13];
  const float* ln2_b    = (const float*)d_in[14];
  const float* ff1_w    = (const float*)d_in[15];
  const float* ff1_b    = (const float*)d_in[16];
  const float* ff2_w    = (const float*)d_in[17];
  const float* ff2_b    = (const float*)d_in[18];
  const float* xcn_w1   = (const float*)d_in[19];
  const float* xcn_b1   = (const float*)d_in[20];
  const float* xcn_w2   = (const float*)d_in[21];
  const float* xcn_b2   = (const float*)d_in[22];
  const float* xcn_w3   = (const float*)d_in[23];
  const float* xcn_b3   = (const float*)d_in[24];
  const float* xij_w1   = (const float*)d_in[25];
  const float* xij_b1   = (const float*)d_in[26];
  const float* xij_w2   = (const float*)d_in[27];
  const float* xij_b2   = (const float*)d_in[28];
  const float* lin_w1   = (const float*)d_in[29];
  const float* lin_b1   = (const float*)d_in[30];
  const float* lin_w2   = (const float*)d_in[31];
  const float* lin_b2   = (const float*)d_in[32];

  u16*   wbf = (u16*)d_ws;
  float* xcn = (float*)((char*)d_ws + (size_t)(2u<<20));   // 4 MB
  float* xij = (float*)((char*)d_ws + (size_t)(6u<<20));   // 4 MB

  WP wp;
  wp.p[0]=tok_w; wp.p[1]=qkv_w; wp.p[2]=out_w; wp.p[3]=ff1_w; wp.p[4]=ff2_w;
  wp.p[5]=xcn_w1; wp.p[6]=xcn_w2; wp.p[7]=xcn_w3; wp.p[8]=xij_w1; wp.p[9]=xij_w2;
  wp.p[10]=lin_w1; wp.p[11]=lin_w2;

  k0_convert<<<dim3(2305), dim3(256), 0, stream>>>(wp, wbf);
  k1_fused<<<dim3(TT/2), dim3(512), 0, stream>>>(
      x, tar_ei, cn_cols, cn_cnt, tok_b, ln1_g, ln1_b, qkv_b, out_b,
      ln2_g, ln2_b, ff1_b, ff2_b, wbf, xcn, xij);
  k2_mlp<<<dim3(TT/16), dim3(256), 0, stream>>>(
      xcn, xij, wbf, xcn_b1, xcn_b2, xcn_b3, xij_b1, xij_b2,
      lin_b1, lin_w2, lin_b2, beta, (float*)d_out);
}

// Round 7
// 529.908 us; speedup vs baseline: 1.8999x; 1.0348x over previous
//
#include <hip/hip_runtime.h>
#include <hip/hip_bf16.h>
#include <math.h>

#define DI __device__ __forceinline__

typedef float  f32x4 __attribute__((ext_vector_type(4)));
typedef short  bf8   __attribute__((ext_vector_type(8)));
typedef unsigned short u16;

static constexpr int TT = 8192;   // T edges
static constexpr int KK = 32;     // CN tokens per edge
static constexpr int CC = 128;    // channels

DI u16 f2bf(float x){ union{float f; unsigned u;} v; v.f = x; unsigned r = v.u + 0x7FFFu + ((v.u>>16)&1u); return (u16)(r>>16); }
DI float bf2f(u16 b){ union{unsigned u; float f;} v; v.u = ((unsigned)b)<<16; return v.f; }
// packed f32->bf16 pair via the official header conversion (RNE); compiler
// lowers/fuses this well (m240: scalar-cast path beat hand-asm cvt_pk).
DI unsigned cvt2(float a, float b){
  union { __hip_bfloat16 h; u16 u; } ta, tb;
  ta.h = __float2bfloat16(a);
  tb.h = __float2bfloat16(b);
  return (unsigned)ta.u | ((unsigned)tb.u << 16);
}
DI f32x4 mfma16(bf8 a, bf8 b, f32x4 c){ return __builtin_amdgcn_mfma_f32_16x16x32_bf16(a, b, c, 0, 0, 0); }
// swizzled LDS byte offset: row-major [*][stride bytes], xor row bits into 16B-slot bits
DI int soff(int r, int c, int stride, int mask){ return r*stride + ((c*2) ^ ((r&mask)<<4)); }

DI bf8 pack8(float4 a, float4 b){
  union { unsigned u[4]; bf8 v; } t;
  t.u[0] = cvt2(a.x, a.y); t.u[1] = cvt2(a.z, a.w);
  t.u[2] = cvt2(b.x, b.y); t.u[3] = cvt2(b.z, b.w);
  return t.v;
}
// store 4 values at (row0..row0+3, colg) — col fixed, rows consecutive
DI void st4(char* base, int row0, int colg, int stride, int mask, f32x4 v){
  unsigned p01 = cvt2(v[0], v[1]), p23 = cvt2(v[2], v[3]);
  *(u16*)(base + soff(row0+0, colg, stride, mask)) = (u16)p01;
  *(u16*)(base + soff(row0+1, colg, stride, mask)) = (u16)(p01 >> 16);
  *(u16*)(base + soff(row0+2, colg, stride, mask)) = (u16)p23;
  *(u16*)(base + soff(row0+3, colg, stride, mask)) = (u16)(p23 >> 16);
}
// store 4 values at (row, col0..col0+3) — row fixed, cols consecutive (8B store)
DI void st4row(char* base, int row, int col0, int stride, int mask, f32x4 v){
  uint2 pv; pv.x = cvt2(v[0], v[1]); pv.y = cvt2(v[2], v[3]);
  *(uint2*)(base + soff(row, col0, stride, mask)) = pv;
}

// ------------------------------------------------------------------
// K0: convert weights fp32 -> bf16 blob in MFMA fragment order:
//   W'[((n16*(K/32) + k32)*64 + l)*8 + e] = W[n16*16 + (l&15)][k32*32 + (l>>4)*8 + e]
// ------------------------------------------------------------------
struct WP { const float* p[12]; };

__global__ void k0_convert(WP wp, u16* __restrict__ dst){
  const int KS[11]  = {512,128,128,128,512,128,256,256,128,256,256};
  const int SH[11]  = {4,2,2,2,4,2,3,3,2,3,3};   // log2(K/32)
  const int OFF[12] = {0,65536,114688,131072,196608,262144,294912,360448,425984,458752,524288,589824};
  int gid = blockIdx.x*256 + threadIdx.x;        // 2305*256 = 590080
  if (gid >= 590080) return;
  if (gid >= 589824){ dst[gid] = f2bf(wp.p[11][gid - 589824]); return; }   // lin_w2 linear
  #pragma unroll
  for (int s = 0; s < 11; s++){
    if (gid < OFF[s+1]){
      int i = gid - OFF[s];
      int e = i & 7, l = (i >> 3) & 63, t = i >> 9;
      int k32 = t & ((1 << SH[s]) - 1), n16 = t >> SH[s];
      int row = n16*16 + (l & 15);
      int col = k32*32 + ((l >> 4) << 3) + e;
      dst[gid] = f2bf(wp.p[s][row*KS[s] + col]);
      return;
    }
  }
}

// ------------------------------------------------------------------
// K1: fused, n-split over 8 waves (512 threads), 2 edges/block.
// Wave w owns output cols [16w,16w+16) in every GEMM.
// Attention: wave = (edge w>>2, head-sub (w>>1)&1, row-half w&1).
// LDS 52K -> 3 blocks/CU = 6 waves/SIMD.
// ------------------------------------------------------------------
#define O_TOK 0        // [64][128] bf16 sw(256,7) 16K residual
#define O_H   16384    // [64][128] bf16 sw(256,7) 16K ln out / xw staging
#define O_RG  32768    // 20480B multi-use (attn bufs / ctx / gelu chunk)
#define LDS_K1 53248

DI void layernorm64(const char* src, char* dst, const float* __restrict__ g,
                    const float* __restrict__ bta, int tid){
  int r = tid >> 3, q = tid & 7;
  float v[16]; float s = 0.f, sq = 0.f;
  #pragma unroll
  for (int i = 0; i < 2; i++){
    bf8 h8 = *(const bf8*)(src + soff(r, q*16 + i*8, 256, 7));
    #pragma unroll
    for (int j = 0; j < 8; j++){ float f = bf2f((u16)h8[j]); v[i*8+j] = f; s += f; sq += f*f; }
  }
  s  += __shfl_xor(s, 1);  s  += __shfl_xor(s, 2);  s  += __shfl_xor(s, 4);
  sq += __shfl_xor(sq, 1); sq += __shfl_xor(sq, 2); sq += __shfl_xor(sq, 4);
  float mu = s * (1.f/128.f);
  float rstd = rsqrtf(sq*(1.f/128.f) - mu*mu + 1e-5f);
  #pragma unroll
  for (int i = 0; i < 2; i++){
    float o[8];
    #pragma unroll
    for (int j = 0; j < 8; j++){
      int c = q*16 + i*8 + j;
      o[j] = (v[i*8+j] - mu)*rstd*g[c] + bta[c];
    }
    union { unsigned u[4]; bf8 v8; } t;
    t.u[0] = cvt2(o[0], o[1]); t.u[1] = cvt2(o[2], o[3]);
    t.u[2] = cvt2(o[4], o[5]); t.u[3] = cvt2(o[6], o[7]);
    *(bf8*)(dst + soff(r, q*16 + i*8, 256, 7)) = t.v8;
  }
}

__global__ __launch_bounds__(512, 6)
void k1_fused(const float* __restrict__ x, const int* __restrict__ tar_ei,
              const int* __restrict__ cn_cols, const int* __restrict__ cn_counts,
              const float* __restrict__ tok_b,
              const float* __restrict__ ln1_g, const float* __restrict__ ln1_b,
              const float* __restrict__ qkv_b, const float* __restrict__ out_b,
              const float* __restrict__ ln2_g, const float* __restrict__ ln2_b,
              const float* __restrict__ ff1_b, const float* __restrict__ ff2_b,
              const u16* __restrict__ wbf,
              u16* __restrict__ xcn_out, u16* __restrict__ xij_out)
{
  __shared__ __align__(16) char sm[LDS_K1];
  const int tid = threadIdx.x;
  const int w = tid >> 6, l = tid & 63, l15 = l & 15, lg = l >> 4;
  const int t0 = blockIdx.x * 2;

  const u16* wtok = wbf;            // [128][512] frag-order
  const u16* wqkv = wbf + 65536;    // [384][128]
  const u16* wout = wbf + 114688;   // [128][128]
  const u16* wff1 = wbf + 131072;   // [512][128]
  const u16* wff2 = wbf + 196608;   // [128][512]

  const f32x4 zf = {0.f, 0.f, 0.f, 0.f};
  const int cnt0 = cn_counts[t0], cnt1 = cn_counts[t0 + 1];
  const int colg = w*16 + l15;      // n-split column for GEMM epilogues

  // ---- phase 0a: gather xw -> sH. 8 threads per row, 16 floats each.
  {
    int r = tid >> 3, q = tid & 7;
    int col = cn_cols[(t0 + (r >> 5))*KK + (r & 31)];
    const float4* xs = (const float4*)(x + (size_t)col*CC) + q*4;
    #pragma unroll
    for (int i = 0; i < 2; i++){
      *(bf8*)(sm + O_H + soff(r, q*16 + i*8, 256, 7)) = pack8(xs[2*i], xs[2*i+1]);
    }
  }
  // ---- phase 0b: stage xi/xj/xi*xj broadcast rows + write xij bf16 (waves 0-1)
  if (w < 2){
    int e = w, c0 = l*2;
    int ti = tar_ei[t0 + e], tj = tar_ei[TT + t0 + e];
    float vix = x[(size_t)ti*CC + c0], viy = x[(size_t)ti*CC + c0 + 1];
    float vjx = x[(size_t)tj*CC + c0], vjy = x[(size_t)tj*CC + c0 + 1];
    float px = vix*vjx, py = viy*vjy;
    unsigned pxy = cvt2(px, py);
    ((unsigned*)xij_out)[(size_t)(t0+e)*64 + l] = pxy;
    unsigned* xb = (unsigned*)(sm + O_RG + 512) + e*192;   // [3][64] u32
    xb[l]       = cvt2(vix, viy);
    xb[64 + l]  = cvt2(vjx, vjy);
    xb[128 + l] = pxy;
  }
  __syncthreads();   // #1

  // ---- tokenlin: n-split; broadcast chunks use identical-row trick (accB)
  {
    f32x4 acc[4], accB[2];
    #pragma unroll
    for (int mt = 0; mt < 4; mt++) acc[mt] = zf;
    accB[0] = zf; accB[1] = zf;
    #pragma unroll
    for (int ks = 0; ks < 4; ks++){
      bf8 b = *(const bf8*)(wtok + ((w*16 + ks)*64 + l)*8);
      #pragma unroll
      for (int mt = 0; mt < 4; mt++){
        bf8 a = *(const bf8*)(sm + O_H + soff(mt*16 + l15, ks*32 + lg*8, 256, 7));
        acc[mt] = mfma16(a, b, acc[mt]);
      }
    }
    #pragma unroll
    for (int c = 1; c < 4; c++){
      #pragma unroll
      for (int ks = 0; ks < 4; ks++){
        bf8 b  = *(const bf8*)(wtok + ((w*16 + c*4 + ks)*64 + l)*8);
        bf8 a0 = *(const bf8*)(sm + O_RG + 512 + 0*768 + (c-1)*256 + (ks*32 + lg*8)*2);
        bf8 a1 = *(const bf8*)(sm + O_RG + 512 + 1*768 + (c-1)*256 + (ks*32 + lg*8)*2);
        accB[0] = mfma16(a0, b, accB[0]);
        accB[1] = mfma16(a1, b, accB[1]);
      }
    }
    float tb = tok_b[colg];
    #pragma unroll
    for (int mt = 0; mt < 4; mt++){
      f32x4 v;
      #pragma unroll
      for (int r = 0; r < 4; r++) v[r] = fmaxf(acc[mt][r] + accB[mt>>1][r] + tb, 0.f);
      st4(sm + O_TOK, mt*16 + lg*4, colg, 256, 7, v);
    }
  }
  __syncthreads();   // #2

  // ---- LN1: sTok -> sH
  layernorm64(sm + O_TOK, sm + O_H, ln1_g, ln1_b, tid);
  __syncthreads();   // #3

  // ---- attention: 4 chunks of 2 heads, 8 waves fully employed
  const int e_w = w >> 2, hs_w = (w >> 1) & 1, hf_w = w & 1;
  const int cnt_e = (e_w == 0) ? cnt0 : cnt1;
  char* const sQ  = sm + O_RG;
  char* const sK  = sm + O_RG + 4096;
  char* const sVT = sm + O_RG + 8192;
  char* const sAT = sm + O_RG + 12288 + (e_w*2 + hs_w)*2048;
  unsigned pkc[4][2];
  #pragma unroll
  for (int hc2 = 0; hc2 < 4; hc2++){
    // qkv: waves 0-3 do q/k (full 64 rows); waves 4-7 do v half-tiles
    if (w < 4){
      int kind = w >> 1, sub = w & 1;
      int n16 = kind*8 + hc2*2 + sub;
      f32x4 acc[4];
      #pragma unroll
      for (int mt = 0; mt < 4; mt++) acc[mt] = zf;
      #pragma unroll
      for (int ks = 0; ks < 4; ks++){
        bf8 b = *(const bf8*)(wqkv + ((n16*4 + ks)*64 + l)*8);
        #pragma unroll
        for (int mt = 0; mt < 4; mt++){
          bf8 a = *(const bf8*)(sm + O_H + soff(mt*16 + l15, ks*32 + lg*8, 256, 7));
          acc[mt] = mfma16(a, b, acc[mt]);
        }
      }
      float bias = qkv_b[n16*16 + l15];
      char* dst = (kind == 0) ? sQ : sK;
      #pragma unroll
      for (int mt = 0; mt < 4; mt++){
        f32x4 v;
        #pragma unroll
        for (int r = 0; r < 4; r++) v[r] = acc[mt][r] + bias;
        st4(dst, mt*16 + lg*4, sub*16 + l15, 64, 3, v);
      }
    } else {
      int sub = (w >> 1) & 1, half = w & 1;
      int n16 = 16 + hc2*2 + sub;
      f32x4 acc[2];
      acc[0] = zf; acc[1] = zf;
      #pragma unroll
      for (int ks = 0; ks < 4; ks++){
        bf8 b = *(const bf8*)(wqkv + ((n16*4 + ks)*64 + l)*8);
        #pragma unroll
        for (int m = 0; m < 2; m++){
          bf8 a = *(const bf8*)(sm + O_H + soff((half*2 + m)*16 + l15, ks*32 + lg*8, 256, 7));
          acc[m] = mfma16(a, b, acc[m]);
        }
      }
      float bias = qkv_b[n16*16 + l15];
      #pragma unroll
      for (int m = 0; m < 2; m++){
        f32x4 v;
        #pragma unroll
        for (int r = 0; r < 4; r++) v[r] = acc[m][r] + bias;
        // VT: row = dh (fixed), cols = 4 consecutive tokens -> one 8B store
        st4row(sVT, sub*16 + l15, (half*2 + m)*16 + lg*4, 128, 7, v);
      }
    }
    __syncthreads();

    // per-wave attention: (edge e_w, head-sub hs_w, row-half hf_w)
    {
      bf8 z8 = {0,0,0,0,0,0,0,0};
      bf8 qa = (lg < 2) ? *(const bf8*)(sQ + soff(e_w*32 + hf_w*16 + l15, hs_w*16 + lg*8, 64, 3)) : z8;
      bf8 kb[2];
      #pragma unroll
      for (int nt = 0; nt < 2; nt++)
        kb[nt] = (lg < 2) ? *(const bf8*)(sK + soff(e_w*32 + nt*16 + l15, hs_w*16 + lg*8, 64, 3)) : z8;
      f32x4 sc[2];
      sc[0] = mfma16(qa, kb[0], zf);
      sc[1] = mfma16(qa, kb[1], zf);
      float pr[2][4];
      #pragma unroll
      for (int nt = 0; nt < 2; nt++)
        #pragma unroll
        for (int r = 0; r < 4; r++)
          pr[nt][r] = (nt*16 + l15 < cnt_e) ? sc[nt][r]*0.25f : -1e9f;
      #pragma unroll
      for (int r = 0; r < 4; r++){
        float m = fmaxf(pr[0][r], pr[1][r]);
        m = fmaxf(m, __shfl_xor(m, 1)); m = fmaxf(m, __shfl_xor(m, 2));
        m = fmaxf(m, __shfl_xor(m, 4)); m = fmaxf(m, __shfl_xor(m, 8));
        float e0 = __expf(pr[0][r] - m), e1 = __expf(pr[1][r] - m);
        float ss = e0 + e1;
        ss += __shfl_xor(ss, 1); ss += __shfl_xor(ss, 2);
        ss += __shfl_xor(ss, 4); ss += __shfl_xor(ss, 8);
        float inv = 1.f / ss;
        int rowl = hf_w*16 + lg*4 + r;
        unsigned p = cvt2(e0*inv, e1*inv);
        *(u16*)(sAT + soff(rowl, l15,      64, 3)) = (u16)p;
        *(u16*)(sAT + soff(rowl, 16 + l15, 64, 3)) = (u16)(p >> 16);
      }
      // PV (reads only this wave's rows; same-wave DS ordering)
      bf8 vb = *(const bf8*)(sVT + soff(hs_w*16 + l15, e_w*32 + lg*8, 128, 7));
      bf8 pa = *(const bf8*)(sAT + soff(hf_w*16 + l15, lg*8, 64, 3));
      f32x4 cx = mfma16(pa, vb, zf);
      pkc[hc2][0] = cvt2(cx[0], cx[1]);
      pkc[hc2][1] = cvt2(cx[2], cx[3]);
    }
    __syncthreads();
  }

  // ---- write ctx to CTX region (overlays attn buffers)
  #pragma unroll
  for (int hc = 0; hc < 4; hc++){
    int head = hc*2 + hs_w;
    int rowbase = e_w*32 + hf_w*16 + lg*4;
    #pragma unroll
    for (int i = 0; i < 2; i++){
      unsigned pv = pkc[hc][i];
      *(u16*)(sm + O_RG + soff(rowbase + i*2,     head*16 + l15, 256, 7)) = (u16)pv;
      *(u16*)(sm + O_RG + soff(rowbase + i*2 + 1, head*16 + l15, 256, 7)) = (u16)(pv >> 16);
    }
  }
  __syncthreads();   // ctx complete

  // ---- out projection + residual (n-split, RMW own TOK cols)
  {
    f32x4 acc[4];
    #pragma unroll
    for (int mt = 0; mt < 4; mt++) acc[mt] = zf;
    #pragma unroll
    for (int ks = 0; ks < 4; ks++){
      bf8 b = *(const bf8*)(wout + ((w*4 + ks)*64 + l)*8);
      #pragma unroll
      for (int mt = 0; mt < 4; mt++){
        bf8 a = *(const bf8*)(sm + O_RG + soff(mt*16 + l15, ks*32 + lg*8, 256, 7));
        acc[mt] = mfma16(a, b, acc[mt]);
      }
    }
    float ob = out_b[colg];
    #pragma unroll
    for (int mt = 0; mt < 4; mt++){
      f32x4 v;
      #pragma unroll
      for (int r = 0; r < 4; r++){
        int rowg = mt*16 + lg*4 + r;
        v[r] = acc[mt][r] + ob + bf2f(*(u16*)(sm + O_TOK + soff(rowg, colg, 256, 7)));
      }
      st4(sm + O_TOK, mt*16 + lg*4, colg, 256, 7, v);
    }
  }
  __syncthreads();

  // ---- LN2: sTok -> sH
  layernorm64(sm + O_TOK, sm + O_H, ln2_g, ln2_b, tid);
  __syncthreads();

  // ---- FF: 4 column chunks of 128; n-split; fp32 acc carried across chunks
  f32x4 acc2[4];
  #pragma unroll
  for (int mt = 0; mt < 4; mt++) acc2[mt] = zf;
  for (int c = 0; c < 4; c++){
    f32x4 acc1[4];
    #pragma unroll
    for (int mt = 0; mt < 4; mt++) acc1[mt] = zf;
    #pragma unroll
    for (int ks = 0; ks < 4; ks++){
      bf8 b = *(const bf8*)(wff1 + (((c*8 + w)*4 + ks)*64 + l)*8);
      #pragma unroll
      for (int mt = 0; mt < 4; mt++){
        bf8 a = *(const bf8*)(sm + O_H + soff(mt*16 + l15, ks*32 + lg*8, 256, 7));
        acc1[mt] = mfma16(a, b, acc1[mt]);
      }
    }
    float fb = ff1_b[c*128 + colg];
    #pragma unroll
    for (int mt = 0; mt < 4; mt++){
      f32x4 g;
      #pragma unroll
      for (int r = 0; r < 4; r++){
        float vv = acc1[mt][r] + fb;
        g[r] = 0.5f*vv*(1.f + erff(vv*0.70710678118654752f));   // exact gelu
      }
      st4(sm + O_RG, mt*16 + lg*4, colg, 256, 7, g);
    }
    __syncthreads();
    #pragma unroll
    for (int ks = 0; ks < 4; ks++){
      bf8 b = *(const bf8*)(wff2 + ((w*16 + c*4 + ks)*64 + l)*8);
      #pragma unroll
      for (int mt = 0; mt < 4; mt++){
        bf8 a = *(const bf8*)(sm + O_RG + soff(mt*16 + l15, ks*32 + lg*8, 256, 7));
        acc2[mt] = mfma16(a, b, acc2[mt]);
      }
    }
    __syncthreads();
  }

  // ---- final residual + masked mean pool (bf16 out to ws)
  {
    float pool[2] = {0.f, 0.f};
    float fb = ff2_b[colg];
    #pragma unroll
    for (int mt = 0; mt < 4; mt++){
      int cnt_m = (mt < 2) ? cnt0 : cnt1;
      #pragma unroll
      for (int r = 0; r < 4; r++){
        int rowg = mt*16 + lg*4 + r;
        float tp = bf2f(*(u16*)(sm + O_TOK + soff(rowg, colg, 256, 7)));
        float v = acc2[mt][r] + fb + tp;
        if ((rowg & 31) < cnt_m) pool[mt >> 1] += v;
      }
    }
    #pragma unroll
    for (int e = 0; e < 2; e++){
      float v = pool[e];
      v += __shfl_xor(v, 16);
      v += __shfl_xor(v, 32);
      if (lg == 0){
        int cn = (e == 0) ? cnt0 : cnt1;
        float denom = (float)(cn > 0 ? cn : 1);
        xcn_out[(size_t)(t0 + e)*CC + colg] = (u16)cvt2(v / denom, 0.f);
      }
    }
  }
}

// ------------------------------------------------------------------
// K2: edge MLPs, 16 edges/block, 512 blocks, 24KB LDS -> 6 blocks/CU.
// Inputs xcn/xij already bf16 in ws -> staging is a pure copy.
// ------------------------------------------------------------------
DI void gemm16(const char* sA, int astride, int ktiles, const u16* __restrict__ W,
               int w, int l, int l15, int lg, f32x4 (&acc)[4]){
  for (int ks = 0; ks < ktiles; ks++){
    bf8 a = *(const bf8*)(sA + soff(l15, ks*32 + lg*8, astride, 7));
    #pragma unroll
    for (int j = 0; j < 4; j++){
      bf8 b = *(const bf8*)(W + (((4*w + j)*ktiles + ks)*64 + l)*8);
      acc[j] = mfma16(a, b, acc[j]);
    }
  }
}

DI void store16(char* dst, f32x4 (&acc)[4], const float* __restrict__ bias, bool relu,
                int w, int l15, int lg){
  #pragma unroll
  for (int j = 0; j < 4; j++){
    int colg = (4*w + j)*16 + l15;
    float bb = bias[colg];
    f32x4 v;
    #pragma unroll
    for (int r = 0; r < 4; r++){
      float vv = acc[j][r] + bb;
      v[r] = relu ? fmaxf(vv, 0.f) : vv;
    }
    st4(dst, lg*4, colg, 512, 7, v);
  }
}

__global__ __launch_bounds__(256, 6)
void k2_mlp(const u16* __restrict__ xcn, const u16* __restrict__ xij,
            const u16* __restrict__ wbf,
            const float* __restrict__ xcn_b1, const float* __restrict__ xcn_b2,
            const float* __restrict__ xcn_b3, const float* __restrict__ xij_b1,
            const float* __restrict__ xij_b2, const float* __restrict__ lin_b1,
            const float* __restrict__ lin_w2, const float* __restrict__ lin_b2,
            const float* __restrict__ beta_p, float* __restrict__ out)
{
  __shared__ __align__(16) char sm[24576];
  const int O_A = 0, O_X = 4096, O_B1 = 8192, O_B2 = 16384;
  const u16* w1  = wbf + 262144;   // [256][128] frag-order
  const u16* w2  = wbf + 294912;   // [256][256]
  const u16* w3  = wbf + 360448;   // [256][256]
  const u16* xw1 = wbf + 425984;   // [256][128]
  const u16* xw2 = wbf + 458752;   // [256][256]
  const u16* lw1 = wbf + 524288;   // [256][256]
  const int tid = threadIdx.x;
  const int w = tid >> 6, l = tid & 63, l15 = tid & 15, lg = (tid & 63) >> 4;
  const int t0 = blockIdx.x * 16;
  const f32x4 zf = {0.f,0.f,0.f,0.f};

  // stage xcn, xij (already bf16): pure 16B copies
  {
    int r = tid >> 4, ci0 = (tid & 15) * 8;
    *(bf8*)(sm + O_A + soff(r, ci0, 256, 7)) = *(const bf8*)(xcn + (size_t)(t0 + r)*CC + ci0);
    *(bf8*)(sm + O_X + soff(r, ci0, 256, 7)) = *(const bf8*)(xij + (size_t)(t0 + r)*CC + ci0);
  }
  __syncthreads();

  f32x4 acc[4];
  // L1: relu(xcn @ w1^T + b1) : A -> B1
  #pragma unroll
  for (int j=0;j<4;j++) acc[j] = zf;
  gemm16(sm + O_A, 256, 4, w1, w, l, l15, lg, acc);
  store16(sm + O_B1, acc, xcn_b1, true, w, l15, lg);
  __syncthreads();
  // L2: relu(h1 @ w2^T + b2) : B1 -> B2
  #pragma unroll
  for (int j=0;j<4;j++) acc[j] = zf;
  gemm16(sm + O_B1, 512, 8, w2, w, l, l15, lg, acc);
  store16(sm + O_B2, acc, xcn_b2, true, w, l15, lg);
  __syncthreads();
  // L3 (no act) B2 -> regs; X1: X -> B1
  f32x4 hc[4];
  #pragma unroll
  for (int j=0;j<4;j++) hc[j] = zf;
  gemm16(sm + O_B2, 512, 8, w3, w, l, l15, lg, hc);
  #pragma unroll
  for (int j=0;j<4;j++) acc[j] = zf;
  gemm16(sm + O_X, 256, 4, xw1, w, l, l15, lg, acc);
  store16(sm + O_B1, acc, xij_b1, true, w, l15, lg);
  __syncthreads();
  // X2 (no act): B1 -> regs; combine -> B2
  f32x4 x2[4];
  #pragma unroll
  for (int j=0;j<4;j++) x2[j] = zf;
  gemm16(sm + O_B1, 512, 8, xw2, w, l, l15, lg, x2);
  {
    float beta = beta_p[0];
    #pragma unroll
    for (int j = 0; j < 4; j++){
      int colg = (4*w + j)*16 + l15;
      float b3v = xcn_b3[colg], xbv = xij_b2[colg];
      f32x4 v;
      #pragma unroll
      for (int r = 0; r < 4; r++)
        v[r] = (hc[j][r] + b3v)*beta + (x2[j][r] + xbv);
      st4(sm + O_B2, lg*4, colg, 512, 7, v);
    }
  }
  __syncthreads();
  // Z: relu(z0 @ lin_w1^T + lin_b1) : B2 -> B1
  #pragma unroll
  for (int j=0;j<4;j++) acc[j] = zf;
  gemm16(sm + O_B2, 512, 8, lw1, w, l, l15, lg, acc);
  store16(sm + O_B1, acc, lin_b1, true, w, l15, lg);
  __syncthreads();
  // final dot with lin_w2 (16 lanes per edge)
  {
    int e = tid >> 4, li = tid & 15;
    float s = 0.f;
    #pragma unroll
    for (int i = 0; i < 16; i++){
      int c = li*16 + i;
      s += bf2f(*(u16*)(sm + O_B1 + soff(e, c, 512, 7))) * lin_w2[c];
    }
    s += __shfl_xor(s, 1); s += __shfl_xor(s, 2);
    s += __shfl_xor(s, 4); s += __shfl_xor(s, 8);
    if (li == 0) out[t0 + e] = s + lin_b2[0];
  }
}

// ------------------------------------------------------------------
extern "C" void kernel_launch(void* const* d_in, const int* in_sizes, int n_in,
                              void* d_out, int out_size, void* d_ws, size_t ws_size,
                              hipStream_t stream){
  (void)in_sizes; (void)n_in; (void)out_size; (void)ws_size;
  const float* x        = (const float*)d_in[0];
  const int*   tar_ei   = (const int*)  d_in[1];
  const int*   cn_cols  = (const int*)  d_in[2];
  const int*   cn_cnt   = (const int*)  d_in[3];
  const float* beta     = (const float*)d_in[4];
  const float* tok_w    = (const float*)d_in[5];
  const float* tok_b    = (const float*)d_in[6];
  const float* ln1_g    = (const float*)d_in[7];
  const float* ln1_b    = (const float*)d_in[8];
  const float* qkv_w    = (const float*)d_in[9];
  const float* qkv_b    = (const float*)d_in[10];
  const float* out_w    = (const float*)d_in[11];
  const float* out_b    = (const float*)d_in[12];
  const float* ln2_g    = (const float*)d_in[13];
  const float* ln2_b    = (const float*)d_in[14];
  const float* ff1_w    = (const float*)d_in[15];
  const float* ff1_b    = (const float*)d_in[16];
  const float* ff2_w    = (const float*)d_in[17];
  const float* ff2_b    = (const float*)d_in[18];
  const float* xcn_w1   = (const float*)d_in[19];
  const float* xcn_b1   = (const float*)d_in[20];
  const float* xcn_w2   = (const float*)d_in[21];
  const float* xcn_b2   = (const float*)d_in[22];
  const float* xcn_w3   = (const float*)d_in[23];
  const float* xcn_b3   = (const float*)d_in[24];
  const float* xij_w1   = (const float*)d_in[25];
  const float* xij_b1   = (const float*)d_in[26];
  const float* xij_w2   = (const float*)d_in[27];
  const float* xij_b2   = (const float*)d_in[28];
  const float* lin_w1   = (const float*)d_in[29];
  const float* lin_b1   = (const float*)d_in[30];
  const float* lin_w2   = (const float*)d_in[31];
  const float* lin_b2   = (const float*)d_in[32];

  u16* wbf = (u16*)d_ws;
  u16* xcn = (u16*)((char*)d_ws + (size_t)(2u<<20));   // 2 MB bf16
  u16* xij = (u16*)((char*)d_ws + (size_t)(4u<<20));   // 2 MB bf16

  WP wp;
  wp.p[0]=tok_w; wp.p[1]=qkv_w; wp.p[2]=out_w; wp.p[3]=ff1_w; wp.p[4]=ff2_w;
  wp.p[5]=xcn_w1; wp.p[6]=xcn_w2; wp.p[7]=xcn_w3; wp.p[8]=xij_w1; wp.p[9]=xij_w2;
  wp.p[10]=lin_w1; wp.p[11]=lin_w2;

  k0_convert<<<dim3(2305), dim3(256), 0, stream>>>(wp, wbf);
  k1_fused<<<dim3(TT/2), dim3(512), 0, stream>>>(
      x, tar_ei, cn_cols, cn_cnt, tok_b, ln1_g, ln1_b, qkv_b, out_b,
      ln2_g, ln2_b, ff1_b, ff2_b, wbf, xcn, xij);
  k2_mlp<<<dim3(TT/16), dim3(256), 0, stream>>>(
      xcn, xij, wbf, xcn_b1, xcn_b2, xcn_b3, xij_b1, xij_b2,
      lin_b1, lin_w2, lin_b2, beta, (float*)d_out);
}